// Round 2
// baseline (3501.604 us; speedup 1.0000x reference)
//
#include <hip/hip_runtime.h>

#define NN 1024
#define MM 1024
#define NB 16
#define BIGF 1.0e10f
#define CW 64                  // chunk width (columns per interval)
#define NCH 16                 // chunks = MM/CW
#define NWV 4                  // waves per block
#define NTHR 256               // 4 waves * 64
#define NIV (NCH + NWV - 1)    // pipeline intervals

__device__ __forceinline__ float softmin3f(float a, float b, float c) {
  float mn = fminf(a, fminf(b, c));
  float s = __expf(mn - a) + __expf(mn - b) + __expf(mn - c);
  return mn - __logf(s);
}

// D[b,i,j] = (x[b,i] - y[j])^2 ; coalesced float4 writes
__global__ __launch_bounds__(256) void d_init_kernel(const float* __restrict__ x,
                                                     const float* __restrict__ y,
                                                     float* __restrict__ D) {
  size_t idx = ((size_t)blockIdx.x * blockDim.x + threadIdx.x) * 4;
  int j = (int)(idx & (MM - 1));
  size_t bi = idx >> 10;
  float xi = x[bi];
  const float4 yv = *reinterpret_cast<const float4*>(y + j);
  float t0 = xi - yv.x, t1 = xi - yv.y, t2 = xi - yv.z, t3 = xi - yv.w;
  float4 o;
  o.x = t0 * t0; o.y = t1 * t1; o.z = t2 * t2; o.w = t3 * t3;
  *reinterpret_cast<float4*>(D + idx) = o;
}

// R boundary: R[b,0,0]=0, R[b,0,j>=1]=BIG, R[b,i>=1,0]=BIG
__global__ __launch_bounds__(1024) void r_bound_kernel(float* __restrict__ R) {
  int b = blockIdx.x, t = threadIdx.x;
  float* Rb = R + (size_t)b * (NN + 1) * (MM + 1);
  Rb[t + 1] = BIGF;
  Rb[(size_t)(t + 1) * (MM + 1)] = BIGF;
  if (t == 0) Rb[0] = 0.0f;
}

// ---------------- forward: 4 waves, 4 rows/lane, shuffle wavefront ----------
// wave w owns rows [256w+1, 256w+256]; lane l owns rows r0..r0+3, r0=256w+4l+1.
// lane l is skewed 1 column behind lane l-1; chunk c processed by wave w at
// interval T = w + c; one __syncthreads per interval.
__global__ __launch_bounds__(NTHR) void sdtw_fwd(const float* __restrict__ x,
                                                 const float* __restrict__ y,
                                                 float* __restrict__ R,
                                                 float* __restrict__ score) {
  __shared__ float bnd[NWV][MM + 2];   // bnd[w][j] = R[256(w+1)][j]
  __shared__ float ylds[MM];
  const int b = blockIdx.x, t = threadIdx.x;
  const int w = t >> 6, l = t & 63;
  const int r0 = (w << 8) + (l << 2) + 1;
  float* __restrict__ Rb = R + (size_t)b * (size_t)(NN + 1) * (MM + 1);
  for (int idx = t; idx < MM; idx += NTHR) ylds[idx] = y[idx];
  if (t < NWV) bnd[t][0] = BIGF;
  const float xa = x[b * NN + r0 - 1];
  const float xb_ = x[b * NN + r0];
  const float xc = x[b * NN + r0 + 1];
  const float xd = x[b * NN + r0 + 2];
  __syncthreads();

  float rm1_0 = BIGF, rm1_1 = BIGF, rm1_2 = BIGF, rm1_3 = BIGF, rm2_3 = BIGF;
  const int wprev = (w > 0) ? (w - 1) : 0;
  const bool isw0 = (w == 0), l0 = (l == 0), l63 = (l == 63);
  const bool wrbnd = l63 && (w < NWV - 1);
  const size_t ro0 = (size_t)r0 * (MM + 1);
  const size_t ro1 = ro0 + (MM + 1);
  const size_t ro2 = ro1 + (MM + 1);
  const size_t ro3 = ro2 + (MM + 1);

  for (int T = 0; T < NIV; ++T) {
    const int c = T - w;
    if (c >= 0 && c < NCH) {
      const int jb = c * CW;
      // lane-0 boundary pipeline (uniform/broadcast LDS reads)
      float bd = bnd[wprev][jb];
      float bu = bnd[wprev][jb + 1];
      float bn1 = bnd[wprev][jb + 2];
      float bn2 = bnd[wprev][jb + 3];
      // y pipeline: cell col j uses y[j-1] = ylds[jb + s - l]
      float y0 = ylds[max(0, jb - l)];
      float y1 = ylds[max(0, jb + 1 - l)];
#pragma unroll 4
      for (int s = 0; s < 128; ++s) {
        const int j = jb + s - l + 1;
        const bool act = (s >= l) && (s - l < CW);
        float up = __shfl_up(rm1_3, 1);   // (r0-1, j)   from lane l-1
        float dg = __shfl_up(rm2_3, 1);   // (r0-1, j-1)
        if (l0) {
          up = isw0 ? BIGF : bu;
          dg = isw0 ? (((jb + s) == 0) ? 0.0f : BIGF) : bd;
        }
        const float ycur = y0;
        // row 0
        {
          float sm = softmin3f(dg, up, rm1_0);
          float dv = xa - ycur; dv *= dv;
          float rnew = dv + sm;
          if (act) Rb[ro0 + j] = rnew;
          dg = rm1_0; up = rnew;
          rm1_0 = act ? rnew : rm1_0;
        }
        // row 1
        {
          float sm = softmin3f(dg, up, rm1_1);
          float dv = xb_ - ycur; dv *= dv;
          float rnew = dv + sm;
          if (act) Rb[ro1 + j] = rnew;
          dg = rm1_1; up = rnew;
          rm1_1 = act ? rnew : rm1_1;
        }
        // row 2
        {
          float sm = softmin3f(dg, up, rm1_2);
          float dv = xc - ycur; dv *= dv;
          float rnew = dv + sm;
          if (act) Rb[ro2 + j] = rnew;
          dg = rm1_2; up = rnew;
          rm1_2 = act ? rnew : rm1_2;
        }
        // row 3 (boundary row of this wave)
        {
          float sm = softmin3f(dg, up, rm1_3);
          float dv = xd - ycur; dv *= dv;
          float rnew = dv + sm;
          if (act) {
            Rb[ro3 + j] = rnew;
            if (wrbnd) bnd[w][j] = rnew;
          }
          rm2_3 = act ? rm1_3 : rm2_3;
          rm1_3 = act ? rnew : rm1_3;
        }
        // rotate pipelines (prefetch distance 2-4)
        bd = bu; bu = bn1; bn1 = bn2;
        bn2 = bnd[wprev][min(jb + s + 4, MM + 1)];
        y0 = y1;
        y1 = ylds[min(MM - 1, max(0, jb + s + 2 - l))];
      }
    }
    __syncthreads();
  }
  if (w == NWV - 1 && l63) score[b] = rm1_3;  // R[N][M]
}

// ---------------- backward: reverse wavefront, same structure ---------------
// Rbar(i,j) = seed + e_dn*exp(r_dn-rij-Ddn) + e_rt*exp(r_rt-rij-Drt)
//                  + e_dg*exp(r_dg-rij-Ddg);  E[i-1][j-1] = Rbar(i,j).
// lane 63 leads (m = 63-l); j = u + m, u = jb + CW - s.
__global__ __launch_bounds__(NTHR) void sdtw_bwd(const float* __restrict__ x,
                                                 const float* __restrict__ y,
                                                 const float* __restrict__ R,
                                                 float* __restrict__ E) {
  __shared__ float ebnd[NWV + 1][MM + 2];  // row 256w+1 Rbar, written by wave w lane 0
  __shared__ float rbnd[NWV + 1][MM + 2];  // row 256w+1 R
  __shared__ float ylds[MM];
  const int b = blockIdx.x, t = threadIdx.x;
  const int w = t >> 6, l = t & 63, m = 63 - l;
  const int r0 = (w << 8) + (l << 2) + 1;
  const float* __restrict__ Rb = R + (size_t)b * (size_t)(NN + 1) * (MM + 1);
  float* __restrict__ Eb = E + (size_t)b * (size_t)NN * MM;
  for (int idx = t; idx < MM; idx += NTHR) ylds[idx] = y[idx];
  for (int idx = t; idx < (NWV + 1) * (MM + 2); idx += NTHR) {
    (&ebnd[0][0])[idx] = 0.0f;
    (&rbnd[0][0])[idx] = 0.0f;
  }
  const float xa = x[b * NN + r0 - 1];               // X(r0)
  const float xb_ = x[b * NN + r0];                  // X(r0+1)
  const float xc = x[b * NN + r0 + 1];               // X(r0+2)
  const float xd = x[b * NN + r0 + 2];               // X(r0+3)
  const float xe = x[b * NN + min(NN - 1, r0 + 3)];  // X(r0+4), clamped (masked)
  __syncthreads();

  float em1_0 = 0.f, em1_1 = 0.f, em1_2 = 0.f, em1_3 = 0.f;
  float rm1_0 = 0.f, rm1_1 = 0.f, rm1_2 = 0.f, rm1_3 = 0.f;
  float em2_0 = 0.f, rm2_0 = 0.f;
  const bool l0 = (l == 0), l63 = (l == 63);
  const bool vdn3 = (r0 + 4 <= NN);
  const bool sdl = (r0 + 3 == NN);
  const size_t ro0 = (size_t)r0 * (MM + 1);
  const size_t ro1 = ro0 + (MM + 1), ro2 = ro1 + (MM + 1), ro3 = ro2 + (MM + 1);
  const size_t eo0 = (size_t)(r0 - 1) * MM;
  const size_t eo1 = eo0 + MM, eo2 = eo1 + MM, eo3 = eo2 + MM;
  // R prefetch rotation registers pf<row><phase>, distance 4 steps
  float pf00, pf01, pf02, pf03, pf10, pf11, pf12, pf13;
  float pf20, pf21, pf22, pf23, pf30, pf31, pf32, pf33;

#define BROW(PF, RM1, EM1, XK1, XK0, VDN, EO)                                  \
  {                                                                            \
    float rij = PF;                                                            \
    float dd1 = XK1 - yjm; dd1 *= dd1;                                         \
    float dd2 = XK0 - yjc; dd2 *= dd2;                                         \
    float dd3 = XK1 - yjc; dd3 *= dd3;                                         \
    float t1 = (VDN) ? (dwn_r - rij - dd1) : -BIGF;                            \
    float t2 = vrt ? (RM1 - rij - dd2) : -BIGF;                                \
    float t3 = ((VDN) && vrt) ? (dgn_r - rij - dd3) : -BIGF;                   \
    acc = dwn_e * __expf(t1) + EM1 * __expf(t2) + dgn_e * __expf(t3);          \
    rijs = rij;                                                                \
  }

#define BSTEP(P)                                                               \
  {                                                                            \
    const int s = s4 * 4 + P;                                                  \
    const int u = jb + CW - s;                                                 \
    const int j = u + m;                                                       \
    const bool act = (s >= m) && (s - m < CW);                                 \
    const bool vrt = (j < MM);                                                 \
    float sdn_e = __shfl_down(em1_0, 1);                                       \
    float sdn_r = __shfl_down(rm1_0, 1);                                       \
    float sdg_e = __shfl_down(em2_0, 1);                                       \
    float sdg_r = __shfl_down(rm2_0, 1);                                       \
    float dwn_e = l63 ? ebc : sdn_e;                                           \
    float dwn_r = l63 ? rbc : sdn_r;                                           \
    float dgn_e = l63 ? ebp : sdg_e;                                           \
    float dgn_r = l63 ? rbp : sdg_r;                                           \
    float acc, rijs;                                                           \
    const int pcol = max(0, min(MM, u - 4 + m));                               \
    /* k=3 */                                                                  \
    BROW(pf3##P, rm1_3, em1_3, xe, xd, vdn3, eo3)                              \
    if (sdl && j == MM) acc += 1.0f;                                           \
    if (act) Eb[eo3 + (j - 1)] = acc;                                          \
    dgn_e = em1_3; dgn_r = rm1_3;                                              \
    em1_3 = act ? acc : em1_3;                                                 \
    rm1_3 = act ? rijs : rm1_3;                                                \
    dwn_e = acc; dwn_r = rijs;                                                 \
    pf3##P = Rb[ro3 + pcol];                                                   \
    /* k=2 */                                                                  \
    BROW(pf2##P, rm1_2, em1_2, xd, xc, true, eo2)                              \
    if (act) Eb[eo2 + (j - 1)] = acc;                                          \
    dgn_e = em1_2; dgn_r = rm1_2;                                              \
    em1_2 = act ? acc : em1_2;                                                 \
    rm1_2 = act ? rijs : rm1_2;                                                \
    dwn_e = acc; dwn_r = rijs;                                                 \
    pf2##P = Rb[ro2 + pcol];                                                   \
    /* k=1 */                                                                  \
    BROW(pf1##P, rm1_1, em1_1, xc, xb_, true, eo1)                             \
    if (act) Eb[eo1 + (j - 1)] = acc;                                          \
    dgn_e = em1_1; dgn_r = rm1_1;                                              \
    em1_1 = act ? acc : em1_1;                                                 \
    rm1_1 = act ? rijs : rm1_1;                                                \
    dwn_e = acc; dwn_r = rijs;                                                 \
    pf1##P = Rb[ro1 + pcol];                                                   \
    /* k=0 */                                                                  \
    BROW(pf0##P, rm1_0, em1_0, xb_, xa, true, eo0)                             \
    if (act) {                                                                 \
      Eb[eo0 + (j - 1)] = acc;                                                 \
      if (l0 && w > 0) { ebnd[w][j] = acc; rbnd[w][j] = rijs; }                \
    }                                                                          \
    em2_0 = act ? em1_0 : em2_0;                                               \
    rm2_0 = act ? rm1_0 : rm2_0;                                               \
    em1_0 = act ? acc : em1_0;                                                 \
    rm1_0 = act ? rijs : rm1_0;                                                \
    pf0##P = Rb[ro0 + pcol];                                                   \
    ebp = ebc; rbp = rbc; ebc = ebn1; rbc = rbn1; ebn1 = ebn2; rbn1 = rbn2;    \
    { int cc2 = max(0, u - 3); ebn2 = ebnd[w + 1][cc2]; rbn2 = rbnd[w + 1][cc2]; } \
    yjc = yjm; yjm = ylds[min(MM - 1, max(0, u + m - 2))];                     \
  }

  for (int T = 0; T < NIV; ++T) {
    const int idxw = T - (NWV - 1 - w);
    if (idxw >= 0 && idxw < NCH) {
      const int c = NCH - 1 - idxw;
      const int jb = c * CW;
      // R prefetch prologue: phases p=0..3 hold cols (jb+CW-p+m)
      {
        const int c0 = min(MM, jb + CW + m);
        const int c1 = min(MM, jb + CW - 1 + m);
        const int c2 = min(MM, jb + CW - 2 + m);
        const int c3 = min(MM, jb + CW - 3 + m);
        pf00 = Rb[ro0 + c0]; pf10 = Rb[ro1 + c0]; pf20 = Rb[ro2 + c0]; pf30 = Rb[ro3 + c0];
        pf01 = Rb[ro0 + c1]; pf11 = Rb[ro1 + c1]; pf21 = Rb[ro2 + c1]; pf31 = Rb[ro3 + c1];
        pf02 = Rb[ro0 + c2]; pf12 = Rb[ro1 + c2]; pf22 = Rb[ro2 + c2]; pf32 = Rb[ro3 + c2];
        pf03 = Rb[ro0 + c3]; pf13 = Rb[ro1 + c3]; pf23 = Rb[ro2 + c3]; pf33 = Rb[ro3 + c3];
      }
      // lane-63 boundary pipelines (uniform LDS reads)
      float ebp = ebnd[w + 1][min(MM + 1, jb + CW + 1)];
      float rbp = rbnd[w + 1][min(MM + 1, jb + CW + 1)];
      float ebc = ebnd[w + 1][jb + CW];
      float rbc = rbnd[w + 1][jb + CW];
      float ebn1 = ebnd[w + 1][jb + CW - 1];
      float rbn1 = rbnd[w + 1][jb + CW - 1];
      float ebn2 = ebnd[w + 1][jb + CW - 2];
      float rbn2 = rbnd[w + 1][jb + CW - 2];
      float yjc = ylds[min(MM - 1, jb + CW + m)];
      float yjm = ylds[min(MM - 1, max(0, jb + CW + m - 1))];
      for (int s4 = 0; s4 < 32; ++s4) {
        BSTEP(0)
        BSTEP(1)
        BSTEP(2)
        BSTEP(3)
      }
    }
    __syncthreads();
  }
#undef BSTEP
#undef BROW
}

extern "C" void kernel_launch(void* const* d_in, const int* in_sizes, int n_in,
                              void* d_out, int out_size, void* d_ws, size_t ws_size,
                              hipStream_t stream) {
  const float* x = (const float*)d_in[0];  // [16, 1024]
  const float* y = (const float*)d_in[1];  // [1024]
  float* out = (float*)d_out;
  float* score = out;                                   // [16]
  float* D = out + NB;                                  // [16,1024,1024]
  float* R = D + (size_t)NB * NN * MM;                  // [16,1025,1025]
  float* E = R + (size_t)NB * (NN + 1) * (MM + 1);      // [16,1024,1024]

  hipLaunchKernelGGL(d_init_kernel, dim3((NB * NN * MM) / (256 * 4)), dim3(256), 0, stream,
                     x, y, D);
  hipLaunchKernelGGL(r_bound_kernel, dim3(NB), dim3(1024), 0, stream, R);
  hipLaunchKernelGGL(sdtw_fwd, dim3(NB), dim3(NTHR), 0, stream, x, y, R, score);
  hipLaunchKernelGGL(sdtw_bwd, dim3(NB), dim3(NTHR), 0, stream, x, y, R, E);
}

// Round 3
// 1820.236 us; speedup vs baseline: 1.9237x; 1.9237x over previous
//
#include <hip/hip_runtime.h>

#define NN 1024
#define MM 1024
#define NB 16
#define BIGF 1.0e10f

typedef float f32x4 __attribute__((ext_vector_type(4)));

__device__ __forceinline__ float softmin3f(float a, float b, float c) {
  float mn = fminf(a, fminf(b, c));
  float s = __expf(mn - a) + __expf(mn - b) + __expf(mn - c);
  return mn - __logf(s);
}

// D[b,i,j] = (x[b,i] - y[j])^2 ; coalesced float4 writes
__global__ __launch_bounds__(256) void d_init_kernel(const float* __restrict__ x,
                                                     const float* __restrict__ y,
                                                     float* __restrict__ D) {
  size_t idx = ((size_t)blockIdx.x * blockDim.x + threadIdx.x) * 4;
  int j = (int)(idx & (MM - 1));
  size_t bi = idx >> 10;
  float xi = x[bi];
  const float4 yv = *reinterpret_cast<const float4*>(y + j);
  float t0 = xi - yv.x, t1 = xi - yv.y, t2 = xi - yv.z, t3 = xi - yv.w;
  float4 o;
  o.x = t0 * t0; o.y = t1 * t1; o.z = t2 * t2; o.w = t3 * t3;
  *reinterpret_cast<float4*>(D + idx) = o;
}

// R boundary: R[b,0,0]=0, R[b,0,j>=1]=BIG, R[b,i>=1,0]=BIG
__global__ __launch_bounds__(1024) void r_bound_kernel(float* __restrict__ R) {
  int b = blockIdx.x, t = threadIdx.x;
  float* Rb = R + (size_t)b * (NN + 1) * (MM + 1);
  Rb[t + 1] = BIGF;
  Rb[(size_t)(t + 1) * (MM + 1)] = BIGF;
  if (t == 0) Rb[0] = 0.0f;
}

// Forward DP: thread t owns row i=t+1. 4-phase rotating LDS diag buffers,
// 16-unrolled phases -> static register ring rv[16], flushed as aligned
// float4s every 16 diagonals (addr mod 16 == 0 since elem addr = i*1024+d).
__global__ __launch_bounds__(1024) void sdtw_fwd(const float* __restrict__ x,
                                                 const float* __restrict__ y,
                                                 float* __restrict__ R,
                                                 float* __restrict__ score) {
  __shared__ float ylds[MM];
  __shared__ float rbuf[4][NN + 1];
  const int b = blockIdx.x, t = threadIdx.x;
  const int i = t + 1;
  float* __restrict__ Rb = R + (size_t)b * (NN + 1) * (MM + 1);
  const size_t rowoff = (size_t)i * (MM + 1);
  ylds[t] = y[t];
  rbuf[0][i] = BIGF; rbuf[1][i] = BIGF; rbuf[2][i] = BIGF; rbuf[3][i] = BIGF;
  if (t == 0) { rbuf[0][0] = 0.0f; rbuf[1][0] = BIGF; rbuf[2][0] = BIGF; rbuf[3][0] = BIGF; }
  const float xi = x[b * NN + t];
  float dg = BIGF;   // R(i-1, j-1), carried: equals previous phase's `up`
  float cc = BIGF;   // R(i, j-1), own previous output
  __syncthreads();
  for (int blk = 0; blk <= 128; ++blk) {
    const int d0 = blk << 4;
    float rv[16];
#pragma unroll
    for (int p = 0; p < 16; ++p) {
      const int d = d0 + p;
      const int j = d - i;
      const bool act = (j >= 1) && (j <= MM);
      const float up = rbuf[(p + 3) & 3][i - 1];   // R(i-1, j), diag d-1
      const float yv = ylds[act ? (j - 1) : 0];
      float dv = xi - yv; dv *= dv;
      const float r = dv + softmin3f(dg, up, cc);
      rbuf[p & 3][i] = act ? r : BIGF;             // maintain BIG when invalid
      if (t == 0 && d >= 1) rbuf[p & 3][0] = BIGF; // row-0 boundary (keep d=0 value 0)
      rv[p] = r;
      if (act) cc = r;
      dg = up;
      __syncthreads();
    }
    // flush 16 cols of own row as 4 aligned float4s (+ scalar edges)
#pragma unroll
    for (int m = 0; m < 4; ++m) {
      const int jm = d0 + 4 * m - i;
      if (jm >= 1 && jm + 3 <= MM) {
        *reinterpret_cast<float4*>(Rb + rowoff + jm) =
            make_float4(rv[4 * m], rv[4 * m + 1], rv[4 * m + 2], rv[4 * m + 3]);
      } else if (jm + 3 >= 1 && jm <= MM) {
#pragma unroll
        for (int c = 0; c < 4; ++c) {
          const int jc = jm + c;
          if (jc >= 1 && jc <= MM) Rb[rowoff + jc] = rv[4 * m + c];
        }
      }
    }
    if (blk == 128 && t == NN - 1) score[b] = rv[0];  // R[N][M] at d=2048
  }
}

// Backward: Rbar(i,j) = seed + E_dn*exp(R_dn-rij-D_dn) + E_rt*exp(R_rt-rij-D_rt)
//                      + E_dg*exp(R_dg-rij-D_dg); E[i-1][j-1] = Rbar(i,j).
// Reverse sweep d = 2063..0 in 16-diag blocks; own-row R prefetched one block
// ahead (aligned float4 into double-buffered regs); E flushed via unaligned
// (4B-aligned) global_store_dwordx4.
__global__ __launch_bounds__(1024) void sdtw_bwd(const float* __restrict__ x,
                                                 const float* __restrict__ y,
                                                 const float* __restrict__ R,
                                                 float* __restrict__ E) {
  __shared__ float ylds[MM];
  __shared__ float rbx[4][NN + 2];
  __shared__ float ebx[4][NN + 2];
  const int b = blockIdx.x, t = threadIdx.x;
  const int i = t + 1;
  const float* __restrict__ Rb = R + (size_t)b * (NN + 1) * (MM + 1);
  float* __restrict__ Eb = E + (size_t)b * (size_t)NN * MM;
  const size_t rowoff = (size_t)i * (MM + 1);
  const size_t eoff = (size_t)(i - 1) * MM;
  ylds[t] = y[t];
#pragma unroll
  for (int q = 0; q < 4; ++q) { rbx[q][i] = -BIGF; ebx[q][i] = 0.0f; }
  if (t == NN - 1) {
#pragma unroll
    for (int q = 0; q < 4; ++q) { rbx[q][NN + 1] = -BIGF; ebx[q][NN + 1] = 0.0f; }
  }
  const float xi = x[b * NN + t];                                  // X(i)
  const float xi1 = x[b * NN + ((t + 1 < NN) ? (t + 1) : t)];      // X(i+1)
  const bool idn = (i + 1 <= NN);
  const bool seedrow = (i == NN);
  float rt_e = 0.0f, rt_r = -BIGF;    // Rbar/R at (i, j+1): own prev phase
  float dgn_e = 0.0f, dgn_r = -BIGF;  // Rbar/R at (i+1, j+1): prev phase's dn
  __syncthreads();
  float yj = ylds[min(MM - 1, max(0, 2063 - i))];  // y[j] rotation seed
  float pfA[16], pfB[16];

#define PREF(PF, KK)                                                           \
  {                                                                            \
    const int dbase = (KK) << 4;                                               \
    _Pragma("unroll")                                                          \
    for (int g = 0; g < 4; ++g) {                                              \
      const int jg = dbase + 4 * g - i;                                        \
      if (jg >= 1 && jg + 3 <= MM) {                                           \
        const float4 v = *reinterpret_cast<const float4*>(Rb + rowoff + jg);   \
        PF[4 * g + 0] = v.x; PF[4 * g + 1] = v.y;                              \
        PF[4 * g + 2] = v.z; PF[4 * g + 3] = v.w;                              \
      } else {                                                                 \
        _Pragma("unroll")                                                      \
        for (int c = 0; c < 4; ++c) {                                          \
          const int jc = jg + c;                                               \
          PF[4 * g + c] = (jc >= 1 && jc <= MM) ? Rb[rowoff + jc] : -BIGF;     \
        }                                                                      \
      }                                                                        \
    }                                                                          \
  }

#define BODY(PFC, PFN, KK)                                                     \
  {                                                                            \
    PREF(PFN, (KK) - 1)                                                        \
    float rv_e[16];                                                            \
    _Pragma("unroll")                                                          \
    for (int p = 0; p < 16; ++p) {                                             \
      const int s = 15 - p;              /* slot = d & 15, descending d */     \
      const int d = ((KK) << 4) + s;                                           \
      const int j = d - i;                                                     \
      const bool act = (j >= 1) && (j <= MM);                                  \
      const bool vrt = (j < MM);                                               \
      const float dn_r = rbx[(s + 1) & 3][i + 1];  /* R(i+1,j), diag d+1 */    \
      const float dn_e = ebx[(s + 1) & 3][i + 1];                              \
      const float yjm1 = ylds[min(MM - 1, max(0, j - 1))];                     \
      const float rij = PFC[s];                                                \
      float d1 = xi1 - yjm1; d1 = d1 * d1;  /* D(i+1, j)   */                  \
      float d2 = xi - yj;    d2 = d2 * d2;  /* D(i,   j+1) */                  \
      float d3 = xi1 - yj;   d3 = d3 * d3;  /* D(i+1, j+1) */                  \
      const float a1 = idn ? (dn_r - rij - d1) : -BIGF;                        \
      const float a2 = vrt ? (rt_r - rij - d2) : -BIGF;                        \
      const float a3 = (idn && vrt) ? (dgn_r - rij - d3) : -BIGF;              \
      float acc = dn_e * __expf(a1) + rt_e * __expf(a2) + dgn_e * __expf(a3);  \
      if (seedrow && j == MM) acc += 1.0f;                                     \
      rbx[s & 3][i] = act ? rij : -BIGF;                                       \
      ebx[s & 3][i] = act ? acc : 0.0f;                                        \
      rv_e[s] = acc;                                                           \
      rt_e = act ? acc : 0.0f;                                                 \
      rt_r = act ? rij : -BIGF;                                                \
      dgn_e = dn_e; dgn_r = dn_r;                                              \
      yj = yjm1;                                                               \
      __syncthreads();                                                         \
    }                                                                          \
    _Pragma("unroll")                                                          \
    for (int g = 0; g < 4; ++g) {                                              \
      const int jg = (((KK) << 4) + 4 * g) - i;                                \
      if (jg >= 1 && jg + 3 <= MM) {                                           \
        f32x4 v;                                                               \
        v[0] = rv_e[4 * g]; v[1] = rv_e[4 * g + 1];                            \
        v[2] = rv_e[4 * g + 2]; v[3] = rv_e[4 * g + 3];                        \
        const float* pp = Eb + eoff + (jg - 1);                                \
        asm volatile("global_store_dwordx4 %0, %1, off" ::"v"(pp), "v"(v)      \
                     : "memory");                                              \
      } else if (jg + 3 >= 1 && jg <= MM) {                                    \
        _Pragma("unroll")                                                      \
        for (int c = 0; c < 4; ++c) {                                          \
          const int jc = jg + c;                                               \
          if (jc >= 1 && jc <= MM) Eb[eoff + (jc - 1)] = rv_e[4 * g + c];      \
        }                                                                      \
      }                                                                        \
    }                                                                          \
  }

  PREF(pfA, 128)
  BODY(pfA, pfB, 128)
  for (int K = 127; K >= 1; K -= 2) {
    BODY(pfB, pfA, K)
    BODY(pfA, pfB, K - 1)
  }
#undef BODY
#undef PREF
}

extern "C" void kernel_launch(void* const* d_in, const int* in_sizes, int n_in,
                              void* d_out, int out_size, void* d_ws, size_t ws_size,
                              hipStream_t stream) {
  const float* x = (const float*)d_in[0];  // [16, 1024]
  const float* y = (const float*)d_in[1];  // [1024]
  float* out = (float*)d_out;
  float* score = out;                                   // [16]
  float* D = out + NB;                                  // [16,1024,1024]
  float* R = D + (size_t)NB * NN * MM;                  // [16,1025,1025]
  float* E = R + (size_t)NB * (NN + 1) * (MM + 1);      // [16,1024,1024]

  hipLaunchKernelGGL(d_init_kernel, dim3((NB * NN * MM) / (256 * 4)), dim3(256), 0, stream,
                     x, y, D);
  hipLaunchKernelGGL(r_bound_kernel, dim3(NB), dim3(1024), 0, stream, R);
  hipLaunchKernelGGL(sdtw_fwd, dim3(NB), dim3(1024), 0, stream, x, y, R, score);
  hipLaunchKernelGGL(sdtw_bwd, dim3(NB), dim3(1024), 0, stream, x, y, R, E);
}

// Round 4
// 1583.021 us; speedup vs baseline: 2.2120x; 1.1498x over previous
//
#include <hip/hip_runtime.h>

#define NN 1024
#define MM 1024
#define NB 16
#define BIGF 1.0e10f
#define TP 17  // padded tile row stride (bank-conflict-free)

typedef float f32x4 __attribute__((ext_vector_type(4)));

__device__ __forceinline__ float softmin3f(float a, float b, float c) {
  float mn = fminf(a, fminf(b, c));
  float s = __expf(mn - a) + __expf(mn - b) + __expf(mn - c);
  return mn - __logf(s);
}

// D[b,i,j] = (x[b,i] - y[j])^2 ; coalesced float4 writes
__global__ __launch_bounds__(256) void d_init_kernel(const float* __restrict__ x,
                                                     const float* __restrict__ y,
                                                     float* __restrict__ D) {
  size_t idx = ((size_t)blockIdx.x * blockDim.x + threadIdx.x) * 4;
  int j = (int)(idx & (MM - 1));
  size_t bi = idx >> 10;
  float xi = x[bi];
  const float4 yv = *reinterpret_cast<const float4*>(y + j);
  float t0 = xi - yv.x, t1 = xi - yv.y, t2 = xi - yv.z, t3 = xi - yv.w;
  float4 o;
  o.x = t0 * t0; o.y = t1 * t1; o.z = t2 * t2; o.w = t3 * t3;
  *reinterpret_cast<float4*>(D + idx) = o;
}

// R boundary: R[b,0,0]=0, R[b,0,j>=1]=BIG, R[b,i>=1,0]=BIG
__global__ __launch_bounds__(1024) void r_bound_kernel(float* __restrict__ R) {
  int b = blockIdx.x, t = threadIdx.x;
  float* Rb = R + (size_t)b * (NN + 1) * (MM + 1);
  Rb[t + 1] = BIGF;
  Rb[(size_t)(t + 1) * (MM + 1)] = BIGF;
  if (t == 0) Rb[0] = 0.0f;
}

// Forward DP: thread t owns row i=t+1; per-diag value goes to LDS tile[t][p];
// every 16 diags the WG cooperatively stores the tile row-major coalesced
// (4 lanes x float4 per row -> 16 rows per wave-instruction).
__global__ __launch_bounds__(1024) void sdtw_fwd(const float* __restrict__ x,
                                                 const float* __restrict__ y,
                                                 float* __restrict__ R,
                                                 float* __restrict__ score) {
  __shared__ float ylds[MM];
  __shared__ float rbuf[4][NN + 1];
  __shared__ float tile[NN][TP];
  const int b = blockIdx.x, t = threadIdx.x;
  const int i = t + 1;
  float* __restrict__ Rb = R + (size_t)b * (NN + 1) * (MM + 1);
  ylds[t] = y[t];
  rbuf[0][i] = BIGF; rbuf[1][i] = BIGF; rbuf[2][i] = BIGF; rbuf[3][i] = BIGF;
  if (t == 0) { rbuf[0][0] = 0.0f; rbuf[1][0] = BIGF; rbuf[2][0] = BIGF; rbuf[3][0] = BIGF; }
  const float xi = x[b * NN + t];
  float dg = BIGF;  // R(i-1, j-1) carry
  float cc = BIGF;  // R(i, j-1) carry
  __syncthreads();
  for (int blk = 0; blk <= 128; ++blk) {
    const int d0 = blk << 4;
#pragma unroll
    for (int p = 0; p < 16; ++p) {
      const int d = d0 + p;
      const int j = d - i;
      const bool act = (j >= 1) && (j <= MM);
      const float up = rbuf[(p + 3) & 3][i - 1];  // R(i-1, j) at diag d-1
      const float yv = ylds[act ? (j - 1) : 0];
      float dv = xi - yv; dv *= dv;
      const float r = dv + softmin3f(dg, up, cc);
      rbuf[p & 3][i] = act ? r : BIGF;
      if (t == 0 && (blk > 0 || p > 0)) rbuf[p & 3][0] = BIGF;  // keep R[0][0]=0 at d=0
      tile[t][p] = r;
      if (act) cc = r;
      dg = up;
      if (blk == 128 && p == 0 && t == NN - 1) score[b] = r;  // R[N][M]
      __syncthreads();
    }
    // cooperative coalesced store: 4 lanes/row, float4 each
#pragma unroll
    for (int pass = 0; pass < 4; ++pass) {
      const int row = (pass << 8) + (t >> 2);  // 0..1023
      const int ir = row + 1;
      const int c4 = (t & 3) << 2;
      const int jb2 = d0 - ir + c4;
      float fv[4];
#pragma unroll
      for (int c = 0; c < 4; ++c) fv[c] = tile[row][c4 + c];
      if (jb2 >= 1 && jb2 + 3 <= MM) {
        *reinterpret_cast<float4*>(Rb + (size_t)ir * (MM + 1) + jb2) =
            make_float4(fv[0], fv[1], fv[2], fv[3]);
      } else if (jb2 + 3 >= 1 && jb2 <= MM) {
#pragma unroll
        for (int c = 0; c < 4; ++c) {
          const int jc = jb2 + c;
          if (jc >= 1 && jc <= MM) Rb[(size_t)ir * (MM + 1) + jc] = fv[c];
        }
      }
    }
    __syncthreads();  // protect tile before next block overwrites
  }
}

// Backward: Rbar(i,j) = seed + E_dn*exp(R_dn-rij-D_dn) + E_rt*exp(R_rt-rij-D_rt)
//                      + E_dg*exp(R_dg-rij-D_dg); E[i-1][j-1] = Rbar(i,j).
// Single LDS tile holds R of the current 16-diag block; each cell's slot is
// overwritten in place with the computed E; block end: coop-store E (unaligned
// dwordx4 asm), coop-load next R block (aligned float4) into the same tile.
__global__ __launch_bounds__(1024) void sdtw_bwd(const float* __restrict__ x,
                                                 const float* __restrict__ y,
                                                 const float* __restrict__ R,
                                                 float* __restrict__ E) {
  __shared__ float ylds[MM];
  __shared__ float rbx[4][NN + 2];
  __shared__ float ebx[4][NN + 2];
  __shared__ float tile[NN][TP];
  const int b = blockIdx.x, t = threadIdx.x;
  const int i = t + 1;
  const float* __restrict__ Rb = R + (size_t)b * (NN + 1) * (MM + 1);
  float* __restrict__ Eb = E + (size_t)b * (size_t)NN * MM;
  ylds[t] = y[t];
#pragma unroll
  for (int q = 0; q < 4; ++q) { rbx[q][i] = -BIGF; ebx[q][i] = 0.0f; }
  if (t == NN - 1) {
#pragma unroll
    for (int q = 0; q < 4; ++q) { rbx[q][NN + 1] = -BIGF; ebx[q][NN + 1] = 0.0f; }
  }
  const float xi = x[b * NN + t];                              // X(i)
  const float xi1 = x[b * NN + ((t + 1 < NN) ? (t + 1) : t)];  // X(i+1)
  const bool idn = (i + 1 <= NN);
  const bool seedrow = (i == NN);
  float rt_e = 0.0f, rt_r = -BIGF;    // (i, j+1) carries
  float dgn_e = 0.0f, dgn_r = -BIGF;  // (i+1, j+1) carries
  // prologue: coop-load R tile for block K=128
#pragma unroll
  for (int pass = 0; pass < 4; ++pass) {
    const int row = (pass << 8) + (t >> 2);
    const int ir = row + 1;
    const int c4 = (t & 3) << 2;
    const int jb2 = (128 << 4) - ir + c4;
    if (jb2 >= 1 && jb2 + 3 <= MM) {
      const float4 v = *reinterpret_cast<const float4*>(Rb + (size_t)ir * (MM + 1) + jb2);
      tile[row][c4] = v.x; tile[row][c4 + 1] = v.y;
      tile[row][c4 + 2] = v.z; tile[row][c4 + 3] = v.w;
    } else {
#pragma unroll
      for (int c = 0; c < 4; ++c) {
        const int jc = jb2 + c;
        tile[row][c4 + c] =
            (jc >= 1 && jc <= MM) ? Rb[(size_t)ir * (MM + 1) + jc] : -BIGF;
      }
    }
  }
  __syncthreads();
  float yj = ylds[min(MM - 1, max(0, 2063 - i))];  // y[j] rotation seed

  for (int K = 128; K >= 0; --K) {
    const int d0 = K << 4;
#pragma unroll
    for (int p = 0; p < 16; ++p) {
      const int s = 15 - p;  // descending d within block
      const int d = d0 + s;
      const int j = d - i;
      const bool act = (j >= 1) && (j <= MM);
      const bool vrt = (j < MM);
      const float dn_r = rbx[(s + 1) & 3][i + 1];  // (i+1, j) at diag d+1
      const float dn_e = ebx[(s + 1) & 3][i + 1];
      const float yjm1 = ylds[min(MM - 1, max(0, j - 1))];
      const float rij = tile[t][s];
      float d1 = xi1 - yjm1; d1 *= d1;  // D(i+1, j)
      float d2 = xi - yj;    d2 *= d2;  // D(i,   j+1)
      float d3 = xi1 - yj;   d3 *= d3;  // D(i+1, j+1)
      const float a1 = idn ? (dn_r - rij - d1) : -BIGF;
      const float a2 = vrt ? (rt_r - rij - d2) : -BIGF;
      const float a3 = (idn && vrt) ? (dgn_r - rij - d3) : -BIGF;
      float acc = dn_e * __expf(a1) + rt_e * __expf(a2) + dgn_e * __expf(a3);
      if (seedrow && j == MM) acc += 1.0f;
      rbx[s & 3][i] = act ? rij : -BIGF;
      ebx[s & 3][i] = act ? acc : 0.0f;
      tile[t][s] = act ? acc : 0.0f;  // in-place E
      rt_e = act ? acc : 0.0f;
      rt_r = act ? rij : -BIGF;
      dgn_e = dn_e; dgn_r = dn_r;
      yj = yjm1;
      __syncthreads();
    }
    // coop: store E tile, then load R tile for block K-1 into same slots
#pragma unroll
    for (int pass = 0; pass < 4; ++pass) {
      const int row = (pass << 8) + (t >> 2);
      const int ir = row + 1;
      const int c4 = (t & 3) << 2;
      const int jb2 = d0 - ir + c4;
      float fv[4];
#pragma unroll
      for (int c = 0; c < 4; ++c) fv[c] = tile[row][c4 + c];
      if (jb2 >= 1 && jb2 + 3 <= MM) {
        f32x4 v;
        v[0] = fv[0]; v[1] = fv[1]; v[2] = fv[2]; v[3] = fv[3];
        const float* pp = Eb + (size_t)row * MM + (jb2 - 1);
        asm volatile("global_store_dwordx4 %0, %1, off" ::"v"(pp), "v"(v) : "memory");
      } else if (jb2 + 3 >= 1 && jb2 <= MM) {
#pragma unroll
        for (int c = 0; c < 4; ++c) {
          const int jc = jb2 + c;
          if (jc >= 1 && jc <= MM) Eb[(size_t)row * MM + (jc - 1)] = fv[c];
        }
      }
      const int jn = jb2 - 16;  // next block window
      if (jn >= 1 && jn + 3 <= MM) {
        const float4 v = *reinterpret_cast<const float4*>(Rb + (size_t)ir * (MM + 1) + jn);
        tile[row][c4] = v.x; tile[row][c4 + 1] = v.y;
        tile[row][c4 + 2] = v.z; tile[row][c4 + 3] = v.w;
      } else {
#pragma unroll
        for (int c = 0; c < 4; ++c) {
          const int jc = jn + c;
          tile[row][c4 + c] =
              (jc >= 1 && jc <= MM) ? Rb[(size_t)ir * (MM + 1) + jc] : -BIGF;
        }
      }
    }
    __syncthreads();
  }
}

extern "C" void kernel_launch(void* const* d_in, const int* in_sizes, int n_in,
                              void* d_out, int out_size, void* d_ws, size_t ws_size,
                              hipStream_t stream) {
  const float* x = (const float*)d_in[0];  // [16, 1024]
  const float* y = (const float*)d_in[1];  // [1024]
  float* out = (float*)d_out;
  float* score = out;                               // [16]
  float* D = out + NB;                              // [16,1024,1024]
  float* R = D + (size_t)NB * NN * MM;              // [16,1025,1025]
  float* E = R + (size_t)NB * (NN + 1) * (MM + 1);  // [16,1024,1024]

  hipLaunchKernelGGL(d_init_kernel, dim3((NB * NN * MM) / (256 * 4)), dim3(256), 0, stream,
                     x, y, D);
  hipLaunchKernelGGL(r_bound_kernel, dim3(NB), dim3(1024), 0, stream, R);
  hipLaunchKernelGGL(sdtw_fwd, dim3(NB), dim3(1024), 0, stream, x, y, R, score);
  hipLaunchKernelGGL(sdtw_bwd, dim3(NB), dim3(1024), 0, stream, x, y, R, E);
}